// Round 14
// baseline (824.760 us; speedup 1.0000x reference)
//
#include <hip/hip_runtime.h>

// Mesh2: out3 = [out1||out2] @ W_comb^T + b_comb ; out4 = mean(self+3nbrs) @ W_agg^T + b_agg
// R5+: linearity split (Y = out2@Wa^T in ws; gather in output space, ~125us proven).
// R9/R12/R13: every staged-pipeline variant (reg, LDS-phase, DMA) serializes on the staging
//   wait -> gemm stuck 390-720us. ROOT CAUSE: the f32->bf16 conversion forces a staging hop.
// R14: kill the hop. conv_kernel pre-converts [out1||out2] -> bf16 C[n][512] (plain layout,
//   written into d_out's out4 region -- dead until gather overwrites it). gemm then reads
//   MFMA A-fragments DIRECTLY from global C (16B/lane contiguous): no LDS, no barriers,
//   no staging, nothing for the compiler to serialize on. B frags from L2 as before.
//   NO nontemporal stores (R10: nt = 4x writes). Scalar MFMA-layout stores (R9-clean).

typedef __bf16 bf16x8 __attribute__((ext_vector_type(8)));
typedef float f32x4 __attribute__((ext_vector_type(4)));

#define N_NODES 200000
#define BM 32
#define NTILES (N_NODES / BM)  // 6250
#define ROWC 520               // fallback only
#define ROWA 264               // fallback only
#define GRID_B 2048
#define GRID_CONV 2048

__device__ __forceinline__ unsigned short f2bf(float x) {
  union { float f; unsigned int u; } v; v.f = x;
  return (unsigned short)((v.u + 0x7FFFu + ((v.u >> 16) & 1u)) >> 16);  // RNE
}

__device__ __forceinline__ void st_bf4(unsigned short* p, float4 f) {
  uint2 w;
  w.x = (unsigned int)f2bf(f.x) | ((unsigned int)f2bf(f.y) << 16);
  w.y = (unsigned int)f2bf(f.z) | ((unsigned int)f2bf(f.w) << 16);
  *reinterpret_cast<uint2*>(p) = w;
}

// Pack W (f32, row-major [O][K]) -> bf16 MFMA-B-fragment-linear layout:
// tile (nt,kt): lane l holds W[nt*16 + (l&15)][kt*32 + (l>>4)*8 + j] at P[tile*512 + l*8 + j].
__global__ void pack_w_kernel(const float* __restrict__ Wc,
                              const float* __restrict__ Wa,
                              unsigned short* __restrict__ Pc,
                              unsigned short* __restrict__ Pa) {
  int t = blockIdx.x * 256 + threadIdx.x;
  if (t >= (512 + 256) * 64) return;
  int lane = t & 63;
  int tile = t >> 6;
  const float* W;
  unsigned short* P;
  int K, kt_n;
  if (tile < 512) { W = Wc; P = Pc; K = 512; kt_n = 16; }
  else { tile -= 512; W = Wa; P = Pa; K = 256; kt_n = 8; }
  int nt = tile / kt_n;
  int kt = tile - nt * kt_n;
  int row = nt * 16 + (lane & 15);
  int k0 = kt * 32 + (lane >> 4) * 8;
  const float* src = W + (size_t)row * K + k0;
  unsigned short* dst = P + (size_t)tile * 512 + lane * 8;
#pragma unroll
  for (int j = 0; j < 8; ++j) dst[j] = f2bf(src[j]);
}

// ---------------- conv: C[n][512] bf16 = [out1[n] || out2[n]] (plain layout) ----------------
__global__ __launch_bounds__(256) void conv_kernel(
    const float* __restrict__ out1, const float* __restrict__ out2,
    unsigned short* __restrict__ C) {
  const int lane = threadIdx.x & 63;
  const int wid = (blockIdx.x * 256 + threadIdx.x) >> 6;
  const int nwaves = (GRID_CONV * 256) >> 6;
  // lane l handles 8 bf16: cols l*8..l*8+7 of the 512-wide row
  for (int n = wid; n < N_NODES; n += nwaves) {
    const float* src = (lane < 32) ? (out1 + (size_t)n * 256 + lane * 8)
                                   : (out2 + (size_t)n * 256 + (lane - 32) * 8);
    float4 f0 = *reinterpret_cast<const float4*>(src);
    float4 f1 = *reinterpret_cast<const float4*>(src + 4);
    uint4 w;
    w.x = (unsigned)f2bf(f0.x) | ((unsigned)f2bf(f0.y) << 16);
    w.y = (unsigned)f2bf(f0.z) | ((unsigned)f2bf(f0.w) << 16);
    w.z = (unsigned)f2bf(f1.x) | ((unsigned)f2bf(f1.y) << 16);
    w.w = (unsigned)f2bf(f1.z) | ((unsigned)f2bf(f1.w) << 16);
    *reinterpret_cast<uint4*>(C + (size_t)n * 512 + lane * 8) = w;
  }
}

// ---------------- Kernel A: barrier-free fragment-direct GEMM (out3 f32 + Y bf16) ----------
__global__ __launch_bounds__(512, 4) void gemm_kernel(
    const unsigned short* __restrict__ C,
    const unsigned short* __restrict__ Pc, const unsigned short* __restrict__ Pa,
    const float* __restrict__ b_comb,
    float* __restrict__ out3, unsigned short* __restrict__ Y) {
  const int tid = threadIdx.x;
  const int wave = tid >> 6, lane = tid & 63;
  const int l15 = lane & 15, l4 = lane >> 4;
  const long long node0 = (long long)blockIdx.x * BM;
  const int nt0 = wave * 4;

  float bcv[4];
#pragma unroll
  for (int n = 0; n < 4; ++n) bcv[n] = b_comb[wave * 64 + n * 16 + l15];

  f32x4 acc3[2][4], accY[2][4];
#pragma unroll
  for (int m = 0; m < 2; ++m)
#pragma unroll
    for (int n = 0; n < 4; ++n) {
      acc3[m][n] = (f32x4){0.f, 0.f, 0.f, 0.f};
      accY[m][n] = (f32x4){0.f, 0.f, 0.f, 0.f};
    }

  // A-fragment base: lane (l15,l4) reads 16B at row l15, byte kt*64 + l4*16.
  // 4 l4-lanes form one contiguous 64B segment; tile (32KB) is L1/L2-resident.
  const unsigned short* a_base = C + (node0 + l15) * 512 + l4 * 8;
  const unsigned short* pc = Pc + (size_t)nt0 * 16 * 512 + lane * 8;
  const unsigned short* pa = Pa + (size_t)nt0 * 8 * 512 + lane * 8;

#pragma unroll
  for (int kt = 0; kt < 16; ++kt) {
    bf16x8 a0 = *reinterpret_cast<const bf16x8*>(a_base + kt * 32);
    bf16x8 a1 = *reinterpret_cast<const bf16x8*>(a_base + 16 * 512 + kt * 32);
#pragma unroll
    for (int n = 0; n < 4; ++n) {
      bf16x8 b = *reinterpret_cast<const bf16x8*>(pc + ((size_t)n * 16 + kt) * 512);
      acc3[0][n] = __builtin_amdgcn_mfma_f32_16x16x32_bf16(a0, b, acc3[0][n], 0, 0, 0);
      acc3[1][n] = __builtin_amdgcn_mfma_f32_16x16x32_bf16(a1, b, acc3[1][n], 0, 0, 0);
    }
    if (kt >= 8) {  // cols 256..511 of C are out2 -> Y = out2 @ Wa^T reuses a0/a1
#pragma unroll
      for (int n = 0; n < 4; ++n) {
        bf16x8 b = *reinterpret_cast<const bf16x8*>(pa + ((size_t)n * 8 + (kt - 8)) * 512);
        accY[0][n] = __builtin_amdgcn_mfma_f32_16x16x32_bf16(a0, b, accY[0][n], 0, 0, 0);
        accY[1][n] = __builtin_amdgcn_mfma_f32_16x16x32_bf16(a1, b, accY[1][n], 0, 0, 0);
      }
    }
  }

  // ---- epilogues: scalar MFMA-layout stores (L2 write-merged; clean per R9/R12) ----
  {
    float* o3 = out3 + node0 * 512 + wave * 64 + l15;
    unsigned short* y = Y + node0 * 512 + wave * 64 + l15;
#pragma unroll
    for (int m = 0; m < 2; ++m)
#pragma unroll
      for (int r = 0; r < 4; ++r) {
        const long long roff = (long long)(m * 16 + l4 * 4 + r) * 512;
        float* p3 = o3 + roff;
        unsigned short* pY = y + roff;
#pragma unroll
        for (int n = 0; n < 4; ++n) {
          p3[n * 16] = acc3[m][n][r] + bcv[n];
          pY[n * 16] = f2bf(accY[m][n][r]);
        }
      }
  }
}

// ---------------- Kernel B: out4 = 0.25*(Y[n]+Y[i0]+Y[i1]+Y[i2]) + b_agg ----------------
__device__ __forceinline__ float bf_lo(unsigned u) {
  union { unsigned x; float f; } c; c.x = u << 16; return c.f;
}
__device__ __forceinline__ float bf_hi(unsigned u) {
  union { unsigned x; float f; } c; c.x = u & 0xFFFF0000u; return c.f;
}

__global__ __launch_bounds__(256) void gather_kernel(
    const unsigned short* __restrict__ Y, const int* __restrict__ nbr,
    const float* __restrict__ b_agg, float* __restrict__ out4) {
  const int lane = threadIdx.x & 63;
  const int wid = (blockIdx.x * 256 + threadIdx.x) >> 6;
  const int nwaves = (GRID_B * 256) >> 6;

  float ba[8];
  const float* bp = b_agg + lane * 8;
#pragma unroll
  for (int j = 0; j < 8; ++j) ba[j] = bp[j];

  for (int n = wid; n < N_NODES; n += nwaves) {
    int i0 = nbr[3 * n + 0];
    int i1 = nbr[3 * n + 1];
    int i2 = nbr[3 * n + 2];
    i0 = i0 < 0 ? 0 : (i0 >= N_NODES ? N_NODES - 1 : i0);
    i1 = i1 < 0 ? 0 : (i1 >= N_NODES ? N_NODES - 1 : i1);
    i2 = i2 < 0 ? 0 : (i2 >= N_NODES ? N_NODES - 1 : i2);

    const uint4 a  = *reinterpret_cast<const uint4*>(Y + (size_t)n  * 512 + lane * 8);
    const uint4 b0 = *reinterpret_cast<const uint4*>(Y + (size_t)i0 * 512 + lane * 8);
    const uint4 b1 = *reinterpret_cast<const uint4*>(Y + (size_t)i1 * 512 + lane * 8);
    const uint4 b2 = *reinterpret_cast<const uint4*>(Y + (size_t)i2 * 512 + lane * 8);

    const unsigned wa[4] = {a.x, a.y, a.z, a.w};
    const unsigned w0[4] = {b0.x, b0.y, b0.z, b0.w};
    const unsigned w1[4] = {b1.x, b1.y, b1.z, b1.w};
    const unsigned w2[4] = {b2.x, b2.y, b2.z, b2.w};
    float s[8];
#pragma unroll
    for (int w = 0; w < 4; ++w) {
      s[2 * w]     = bf_lo(wa[w]) + bf_lo(w0[w]) + bf_lo(w1[w]) + bf_lo(w2[w]);
      s[2 * w + 1] = bf_hi(wa[w]) + bf_hi(w0[w]) + bf_hi(w1[w]) + bf_hi(w2[w]);
    }
    f32x4 o0 = {s[0] * 0.25f + ba[0], s[1] * 0.25f + ba[1],
                s[2] * 0.25f + ba[2], s[3] * 0.25f + ba[3]};
    f32x4 o1 = {s[4] * 0.25f + ba[4], s[5] * 0.25f + ba[5],
                s[6] * 0.25f + ba[6], s[7] * 0.25f + ba[7]};
    f32x4* op = reinterpret_cast<f32x4*>(out4 + (size_t)n * 512 + lane * 8);
    op[0] = o0;  // plain cached stores — nt inflates HBM writes 4x on gfx950 (R10)
    op[1] = o1;
  }
}

// ---------------- Fallback (R2-style, known-good) if ws too small for Y ----------------
__global__ __launch_bounds__(512, 4) void mesh_fused_fallback(
    const float* __restrict__ out1, const float* __restrict__ out2,
    const int* __restrict__ nbr,
    const unsigned short* __restrict__ Pc, const unsigned short* __restrict__ Pa,
    const float* __restrict__ b_comb, const float* __restrict__ b_agg,
    float* __restrict__ outp) {
  __shared__ unsigned short Ac[32 * ROWC];
  __shared__ unsigned short Aagg[32 * ROWA];
  const int tid = threadIdx.x;
  const long long node0 = (long long)blockIdx.x * 32;
  {
    const int ln = tid >> 4, c16 = tid & 15;
    const long long gn = node0 + ln;
    long long i0 = nbr[3 * gn + 0], i1 = nbr[3 * gn + 1], i2 = nbr[3 * gn + 2];
    i0 = i0 < 0 ? 0 : (i0 >= N_NODES ? N_NODES - 1 : i0);
    i1 = i1 < 0 ? 0 : (i1 >= N_NODES ? N_NODES - 1 : i1);
    i2 = i2 < 0 ? 0 : (i2 >= N_NODES ? N_NODES - 1 : i2);
    const float4* r1 = reinterpret_cast<const float4*>(out1 + gn * 256);
    const float4* r2 = reinterpret_cast<const float4*>(out2 + gn * 256);
    const float4* g0 = reinterpret_cast<const float4*>(out2 + i0 * 256);
    const float4* g1 = reinterpret_cast<const float4*>(out2 + i1 * 256);
    const float4* g2 = reinterpret_cast<const float4*>(out2 + i2 * 256);
#pragma unroll
    for (int r = 0; r < 4; ++r) {
      const int c = c16 + 16 * r;
      float4 f1 = r1[c], f2 = r2[c], n0 = g0[c], n1 = g1[c], n2 = g2[c];
      float4 ag;
      ag.x = (f2.x + n0.x + n1.x + n2.x) * 0.25f;
      ag.y = (f2.y + n0.y + n1.y + n2.y) * 0.25f;
      ag.z = (f2.z + n0.z + n1.z + n2.z) * 0.25f;
      ag.w = (f2.w + n0.w + n1.w + n2.w) * 0.25f;
      st_bf4(&Ac[ln * ROWC + c * 4], f1);
      st_bf4(&Ac[ln * ROWC + 256 + c * 4], f2);
      st_bf4(&Aagg[ln * ROWA + c * 4], ag);
    }
  }
  __syncthreads();
  const int wave = tid >> 6, lane = tid & 63;
  const int l15 = lane & 15, l4 = lane >> 4;
  const int nt0 = wave * 4;
  float* o3 = outp;
  float* o4 = outp + (size_t)N_NODES * 512;
  {
    f32x4 acc[2][4];
#pragma unroll
    for (int m = 0; m < 2; ++m)
#pragma unroll
      for (int n = 0; n < 4; ++n) acc[m][n] = (f32x4){0.f, 0.f, 0.f, 0.f};
    const unsigned short* pc = Pc + (size_t)nt0 * 16 * 512 + lane * 8;
    const unsigned short* ab = &Ac[(size_t)l15 * ROWC + l4 * 8];
#pragma unroll
    for (int kt = 0; kt < 16; ++kt) {
      bf16x8 a0 = *reinterpret_cast<const bf16x8*>(ab + kt * 32);
      bf16x8 a1 = *reinterpret_cast<const bf16x8*>(ab + 16 * ROWC + kt * 32);
#pragma unroll
      for (int n = 0; n < 4; ++n) {
        bf16x8 bb = *reinterpret_cast<const bf16x8*>(pc + ((size_t)n * 16 + kt) * 512);
        acc[0][n] = __builtin_amdgcn_mfma_f32_16x16x32_bf16(a0, bb, acc[0][n], 0, 0, 0);
        acc[1][n] = __builtin_amdgcn_mfma_f32_16x16x32_bf16(a1, bb, acc[1][n], 0, 0, 0);
      }
    }
#pragma unroll
    for (int m = 0; m < 2; ++m)
#pragma unroll
      for (int r = 0; r < 4; ++r)
#pragma unroll
        for (int n = 0; n < 4; ++n) {
          const int col = wave * 64 + n * 16 + l15;
          o3[(node0 + m * 16 + l4 * 4 + r) * 512 + col] = acc[m][n][r] + b_comb[col];
        }
  }
  {
    f32x4 acc[2][4];
#pragma unroll
    for (int m = 0; m < 2; ++m)
#pragma unroll
      for (int n = 0; n < 4; ++n) acc[m][n] = (f32x4){0.f, 0.f, 0.f, 0.f};
    const unsigned short* pa = Pa + (size_t)nt0 * 8 * 512 + lane * 8;
    const unsigned short* ab = &Aagg[(size_t)l15 * ROWA + l4 * 8];
#pragma unroll
    for (int kt = 0; kt < 8; ++kt) {
      bf16x8 a0 = *reinterpret_cast<const bf16x8*>(ab + kt * 32);
      bf16x8 a1 = *reinterpret_cast<const bf16x8*>(ab + 16 * ROWA + kt * 32);
#pragma unroll
      for (int n = 0; n < 4; ++n) {
        bf16x8 bb = *reinterpret_cast<const bf16x8*>(pa + ((size_t)n * 8 + kt) * 512);
        acc[0][n] = __builtin_amdgcn_mfma_f32_16x16x32_bf16(a0, bb, acc[0][n], 0, 0, 0);
        acc[1][n] = __builtin_amdgcn_mfma_f32_16x16x32_bf16(a1, bb, acc[1][n], 0, 0, 0);
      }
    }
#pragma unroll
    for (int m = 0; m < 2; ++m)
#pragma unroll
      for (int r = 0; r < 4; ++r)
#pragma unroll
        for (int n = 0; n < 4; ++n) {
          const int col = wave * 64 + n * 16 + l15;
          o4[(node0 + m * 16 + l4 * 4 + r) * 512 + col] = acc[m][n][r] + b_agg[col];
        }
  }
}

extern "C" void kernel_launch(void* const* d_in, const int* in_sizes, int n_in,
                              void* d_out, int out_size, void* d_ws, size_t ws_size,
                              hipStream_t stream) {
  const float* out1 = (const float*)d_in[0];
  const float* out2 = (const float*)d_in[1];
  const int* nbr = (const int*)d_in[2];  // harness pushes integers as int32
  const float* Wc = (const float*)d_in[3];
  const float* bc = (const float*)d_in[4];
  const float* Wa = (const float*)d_in[5];
  const float* ba = (const float*)d_in[6];

  const size_t yElems = (size_t)N_NODES * 512;     // bf16 Y: 204.8 MB (in ws)
  const size_t packElems = 512 * 512 + 512 * 256;  // 768 KB
  const size_t need = (yElems + packElems) * 2;    // bytes

  if (ws_size >= need) {
    unsigned short* Yw = (unsigned short*)d_ws;
    unsigned short* Pc = Yw + yElems;
    unsigned short* Pa = Pc + 512 * 512;
    float* out3 = (float*)d_out;
    float* out4 = out3 + (size_t)N_NODES * 512;
    // C (bf16, 205MB) lives in the out4 region of d_out: dead until gather overwrites it.
    unsigned short* Cbuf = (unsigned short*)out4;

    pack_w_kernel<<<192, 256, 0, stream>>>(Wc, Wa, Pc, Pa);
    conv_kernel<<<GRID_CONV, 256, 0, stream>>>(out1, out2, Cbuf);
    gemm_kernel<<<NTILES, 512, 0, stream>>>(Cbuf, Pc, Pa, bc, out3, Yw);
    gather_kernel<<<GRID_B, 256, 0, stream>>>(Yw, nbr, ba, out4);
  } else {
    unsigned short* Pc = (unsigned short*)d_ws;
    unsigned short* Pa = Pc + 512 * 512;
    pack_w_kernel<<<192, 256, 0, stream>>>(Wc, Wa, Pc, Pa);
    mesh_fused_fallback<<<N_NODES / 32, 512, 0, stream>>>(out1, out2, nbr, Pc, Pa, bc, ba,
                                                          (float*)d_out);
  }
}

// Round 15
// 521.981 us; speedup vs baseline: 1.5801x; 1.5801x over previous
//
#include <hip/hip_runtime.h>

// Mesh2: out3 = [out1||out2] @ W_comb^T + b_comb ; out4 = mean(self+3nbrs) @ W_agg^T + b_agg
// R15: RESTORATION of the measured session optimum (R7 artifact, 521.8us total:
//   gemm ~390, gather ~125, pack ~5). Campaign summary:
//   - Linearity split (Y = out2@Wa^T in ws; gather AFTER GEMM in output space): -80us, banked.
//   - Clean stores: no nontemporal on out3/bounced stores (R10: nt = 4x WRITE on gfx950);
//     scalar MFMA-layout f32 stores are L2-merged clean (R9/R12 counters).
//   - Every pipelining attempt regressed: reg-prefetch spills or serializes (R3/R4/R6/R12),
//     per-phase vmcnt(0) drains serialize (R9/R13), interleaved acc overflows the 64-VGPR
//     cap that launch_bounds(512,4) implies (R14). R7's sequential-scope simple structure
//     with 4 blocks/CU TLP is the hipcc-compatible optimum for this shape.

typedef __bf16 bf16x8 __attribute__((ext_vector_type(8)));
typedef float f32x4 __attribute__((ext_vector_type(4)));

#define N_NODES 200000
#define BM 32
#define NTILES (N_NODES / BM)  // 6250
#define ROWC 520               // 512 + 8 pad (bf16) -> conflict-free quarter-wave b128
#define ROWA 264               // fallback only
#define GRID_B 2048

__device__ __forceinline__ unsigned short f2bf(float x) {
  union { float f; unsigned int u; } v; v.f = x;
  return (unsigned short)((v.u + 0x7FFFu + ((v.u >> 16) & 1u)) >> 16);  // RNE
}

__device__ __forceinline__ void st_bf4(unsigned short* p, float4 f) {
  uint2 w;
  w.x = (unsigned int)f2bf(f.x) | ((unsigned int)f2bf(f.y) << 16);
  w.y = (unsigned int)f2bf(f.z) | ((unsigned int)f2bf(f.w) << 16);
  *reinterpret_cast<uint2*>(p) = w;
}

// Pack W (f32, row-major [O][K]) -> bf16 MFMA-B-fragment-linear layout:
// tile (nt,kt): lane l holds W[nt*16 + (l&15)][kt*32 + (l>>4)*8 + j] at P[tile*512 + l*8 + j].
__global__ void pack_w_kernel(const float* __restrict__ Wc,
                              const float* __restrict__ Wa,
                              unsigned short* __restrict__ Pc,
                              unsigned short* __restrict__ Pa) {
  int t = blockIdx.x * 256 + threadIdx.x;
  if (t >= (512 + 256) * 64) return;
  int lane = t & 63;
  int tile = t >> 6;
  const float* W;
  unsigned short* P;
  int K, kt_n;
  if (tile < 512) { W = Wc; P = Pc; K = 512; kt_n = 16; }
  else { tile -= 512; W = Wa; P = Pa; K = 256; kt_n = 8; }
  int nt = tile / kt_n;
  int kt = tile - nt * kt_n;
  int row = nt * 16 + (lane & 15);
  int k0 = kt * 32 + (lane >> 4) * 8;
  const float* src = W + (size_t)row * K + k0;
  unsigned short* dst = P + (size_t)tile * 512 + lane * 8;
#pragma unroll
  for (int j = 0; j < 8; ++j) dst[j] = f2bf(src[j]);
}

// ---------------- Kernel A: dense GEMM (out3 f32 + Y bf16), simple R2 structure ----------------
__global__ __launch_bounds__(512, 4) void gemm_kernel(
    const float* __restrict__ out1, const float* __restrict__ out2,
    const unsigned short* __restrict__ Pc, const unsigned short* __restrict__ Pa,
    const float* __restrict__ b_comb,
    float* __restrict__ out3, unsigned short* __restrict__ Y) {
  __shared__ unsigned short Acomb[BM * ROWC];  // 33.3 KB -> 4 blocks/CU

  const int tid = threadIdx.x;
  const int ln = tid >> 4, c16 = tid & 15;  // stage role: node, chunk
  const int wave = tid >> 6, lane = tid & 63;
  const int l15 = lane & 15, l4 = lane >> 4;
  const long long node0 = (long long)blockIdx.x * BM;

  // ---- stage: 16 threads/node, out1|out2 -> bf16 LDS ----
  {
    const size_t gn = (size_t)node0 + ln;
    const float4* r1 = reinterpret_cast<const float4*>(out1 + gn * 256);
    const float4* r2 = reinterpret_cast<const float4*>(out2 + gn * 256);
#pragma unroll
    for (int r = 0; r < 4; ++r) {
      const int cc = c16 + 16 * r;
      st_bf4(&Acomb[ln * ROWC + cc * 4], r1[cc]);        // cols 0..255   = out1
      st_bf4(&Acomb[ln * ROWC + 256 + cc * 4], r2[cc]);  // cols 256..511 = out2
    }
  }
  __syncthreads();

  const int nt0 = wave * 4;

  // ---- out3 = [o1|o2] @ Wc^T + b (K=512) ----
  {
    f32x4 acc[2][4];
#pragma unroll
    for (int m = 0; m < 2; ++m)
#pragma unroll
      for (int n = 0; n < 4; ++n) acc[m][n] = (f32x4){0.f, 0.f, 0.f, 0.f};

    const unsigned short* pc = Pc + (size_t)nt0 * 16 * 512 + lane * 8;
    const unsigned short* ab = &Acomb[(size_t)l15 * ROWC + l4 * 8];
#pragma unroll
    for (int kt = 0; kt < 16; ++kt) {
      bf16x8 a0 = *reinterpret_cast<const bf16x8*>(ab + kt * 32);
      bf16x8 a1 = *reinterpret_cast<const bf16x8*>(ab + 16 * ROWC + kt * 32);
      bf16x8 bfr[4];
#pragma unroll
      for (int n = 0; n < 4; ++n)
        bfr[n] = *reinterpret_cast<const bf16x8*>(pc + ((size_t)n * 16 + kt) * 512);
#pragma unroll
      for (int n = 0; n < 4; ++n) {
        acc[0][n] = __builtin_amdgcn_mfma_f32_16x16x32_bf16(a0, bfr[n], acc[0][n], 0, 0, 0);
        acc[1][n] = __builtin_amdgcn_mfma_f32_16x16x32_bf16(a1, bfr[n], acc[1][n], 0, 0, 0);
      }
    }
    float* o3 = out3 + node0 * 512 + wave * 64 + l15;
#pragma unroll
    for (int m = 0; m < 2; ++m)
#pragma unroll
      for (int r = 0; r < 4; ++r) {
        float* p = o3 + (long long)(m * 16 + l4 * 4 + r) * 512;
#pragma unroll
        for (int n = 0; n < 4; ++n)
          p[n * 16] = acc[m][n][r] + b_comb[wave * 64 + n * 16 + l15];
      }
  }

  // ---- Y = o2 @ Wa^T (K=256, A = Acomb cols 256..511), frags -> LDS -> coalesced ----
  {
    f32x4 acc[2][4];
#pragma unroll
    for (int m = 0; m < 2; ++m)
#pragma unroll
      for (int n = 0; n < 4; ++n) acc[m][n] = (f32x4){0.f, 0.f, 0.f, 0.f};

    const unsigned short* pa = Pa + (size_t)nt0 * 8 * 512 + lane * 8;
    const unsigned short* ab = &Acomb[(size_t)l15 * ROWC + 256 + l4 * 8];
#pragma unroll
    for (int kt = 0; kt < 8; ++kt) {
      bf16x8 a0 = *reinterpret_cast<const bf16x8*>(ab + kt * 32);
      bf16x8 a1 = *reinterpret_cast<const bf16x8*>(ab + 16 * ROWC + kt * 32);
      bf16x8 bfr[4];
#pragma unroll
      for (int n = 0; n < 4; ++n)
        bfr[n] = *reinterpret_cast<const bf16x8*>(pa + ((size_t)n * 8 + kt) * 512);
#pragma unroll
      for (int n = 0; n < 4; ++n) {
        acc[0][n] = __builtin_amdgcn_mfma_f32_16x16x32_bf16(a0, bfr[n], acc[0][n], 0, 0, 0);
        acc[1][n] = __builtin_amdgcn_mfma_f32_16x16x32_bf16(a1, bfr[n], acc[1][n], 0, 0, 0);
      }
    }

    __syncthreads();  // all waves' LDS reads done -> safe to overwrite Acomb
#pragma unroll
    for (int m = 0; m < 2; ++m)
#pragma unroll
      for (int r = 0; r < 4; ++r) {
        const int row = m * 16 + l4 * 4 + r;
#pragma unroll
        for (int n = 0; n < 4; ++n)
          Acomb[row * ROWC + wave * 64 + n * 16 + l15] = f2bf(acc[m][n][r]);
      }
    __syncthreads();  // Y tile assembled in LDS

    // coalesced copy-out: 256B contiguous per quarter-wave, cached (gather reuses via L2/L3)
    {
      const int row = tid >> 4;
      const unsigned short* src = &Acomb[row * ROWC];
      unsigned short* dst = Y + (node0 + row) * 512;
#pragma unroll
      for (int j = 0; j < 4; ++j) {
        const int off = (c16 + 16 * j) * 8;
        *reinterpret_cast<uint4*>(dst + off) =
            *reinterpret_cast<const uint4*>(src + off);
      }
    }
  }
}

// ---------------- Kernel B: out4 = 0.25*(Y[n]+Y[i0]+Y[i1]+Y[i2]) + b_agg ----------------
__device__ __forceinline__ float bf_lo(unsigned u) {
  union { unsigned x; float f; } c; c.x = u << 16; return c.f;
}
__device__ __forceinline__ float bf_hi(unsigned u) {
  union { unsigned x; float f; } c; c.x = u & 0xFFFF0000u; return c.f;
}

__global__ __launch_bounds__(256) void gather_kernel(
    const unsigned short* __restrict__ Y, const int* __restrict__ nbr,
    const float* __restrict__ b_agg, float* __restrict__ out4) {
  const int lane = threadIdx.x & 63;
  const int wid = (blockIdx.x * 256 + threadIdx.x) >> 6;
  const int nwaves = (GRID_B * 256) >> 6;

  float ba[8];
  const float* bp = b_agg + lane * 8;
#pragma unroll
  for (int j = 0; j < 8; ++j) ba[j] = bp[j];

  for (int n = wid; n < N_NODES; n += nwaves) {
    int i0 = nbr[3 * n + 0];
    int i1 = nbr[3 * n + 1];
    int i2 = nbr[3 * n + 2];
    i0 = i0 < 0 ? 0 : (i0 >= N_NODES ? N_NODES - 1 : i0);
    i1 = i1 < 0 ? 0 : (i1 >= N_NODES ? N_NODES - 1 : i1);
    i2 = i2 < 0 ? 0 : (i2 >= N_NODES ? N_NODES - 1 : i2);

    const uint4 a  = *reinterpret_cast<const uint4*>(Y + (size_t)n  * 512 + lane * 8);
    const uint4 b0 = *reinterpret_cast<const uint4*>(Y + (size_t)i0 * 512 + lane * 8);
    const uint4 b1 = *reinterpret_cast<const uint4*>(Y + (size_t)i1 * 512 + lane * 8);
    const uint4 b2 = *reinterpret_cast<const uint4*>(Y + (size_t)i2 * 512 + lane * 8);

    const unsigned wa[4] = {a.x, a.y, a.z, a.w};
    const unsigned w0[4] = {b0.x, b0.y, b0.z, b0.w};
    const unsigned w1[4] = {b1.x, b1.y, b1.z, b1.w};
    const unsigned w2[4] = {b2.x, b2.y, b2.z, b2.w};
    float s[8];
#pragma unroll
    for (int w = 0; w < 4; ++w) {
      s[2 * w]     = bf_lo(wa[w]) + bf_lo(w0[w]) + bf_lo(w1[w]) + bf_lo(w2[w]);
      s[2 * w + 1] = bf_hi(wa[w]) + bf_hi(w0[w]) + bf_hi(w1[w]) + bf_hi(w2[w]);
    }
    f32x4 o0 = {s[0] * 0.25f + ba[0], s[1] * 0.25f + ba[1],
                s[2] * 0.25f + ba[2], s[3] * 0.25f + ba[3]};
    f32x4 o1 = {s[4] * 0.25f + ba[4], s[5] * 0.25f + ba[5],
                s[6] * 0.25f + ba[6], s[7] * 0.25f + ba[7]};
    f32x4* op = reinterpret_cast<f32x4*>(out4 + (size_t)n * 512 + lane * 8);
    __builtin_nontemporal_store(o0, op);
    __builtin_nontemporal_store(o1, op + 1);
  }
}

// ---------------- Fallback (R2-style, known-good) if ws too small for Y ----------------
__global__ __launch_bounds__(512, 4) void mesh_fused_fallback(
    const float* __restrict__ out1, const float* __restrict__ out2,
    const int* __restrict__ nbr,
    const unsigned short* __restrict__ Pc, const unsigned short* __restrict__ Pa,
    const float* __restrict__ b_comb, const float* __restrict__ b_agg,
    float* __restrict__ outp) {
  __shared__ unsigned short Ac[32 * ROWC];
  __shared__ unsigned short Aagg[32 * ROWA];
  const int tid = threadIdx.x;
  const long long node0 = (long long)blockIdx.x * 32;
  {
    const int ln = tid >> 4, c16 = tid & 15;
    const long long gn = node0 + ln;
    long long i0 = nbr[3 * gn + 0], i1 = nbr[3 * gn + 1], i2 = nbr[3 * gn + 2];
    i0 = i0 < 0 ? 0 : (i0 >= N_NODES ? N_NODES - 1 : i0);
    i1 = i1 < 0 ? 0 : (i1 >= N_NODES ? N_NODES - 1 : i1);
    i2 = i2 < 0 ? 0 : (i2 >= N_NODES ? N_NODES - 1 : i2);
    const float4* r1 = reinterpret_cast<const float4*>(out1 + gn * 256);
    const float4* r2 = reinterpret_cast<const float4*>(out2 + gn * 256);
    const float4* g0 = reinterpret_cast<const float4*>(out2 + i0 * 256);
    const float4* g1 = reinterpret_cast<const float4*>(out2 + i1 * 256);
    const float4* g2 = reinterpret_cast<const float4*>(out2 + i2 * 256);
#pragma unroll
    for (int r = 0; r < 4; ++r) {
      const int c = c16 + 16 * r;
      float4 f1 = r1[c], f2 = r2[c], n0 = g0[c], n1 = g1[c], n2 = g2[c];
      float4 ag;
      ag.x = (f2.x + n0.x + n1.x + n2.x) * 0.25f;
      ag.y = (f2.y + n0.y + n1.y + n2.y) * 0.25f;
      ag.z = (f2.z + n0.z + n1.z + n2.z) * 0.25f;
      ag.w = (f2.w + n0.w + n1.w + n2.w) * 0.25f;
      st_bf4(&Ac[ln * ROWC + c * 4], f1);
      st_bf4(&Ac[ln * ROWC + 256 + c * 4], f2);
      st_bf4(&Aagg[ln * ROWA + c * 4], ag);
    }
  }
  __syncthreads();
  const int wave = tid >> 6, lane = tid & 63;
  const int l15 = lane & 15, l4 = lane >> 4;
  const int nt0 = wave * 4;
  float* o3 = outp;
  float* o4 = outp + (size_t)N_NODES * 512;
  {
    f32x4 acc[2][4];
#pragma unroll
    for (int m = 0; m < 2; ++m)
#pragma unroll
      for (int n = 0; n < 4; ++n) acc[m][n] = (f32x4){0.f, 0.f, 0.f, 0.f};
    const unsigned short* pc = Pc + (size_t)nt0 * 16 * 512 + lane * 8;
    const unsigned short* ab = &Ac[(size_t)l15 * ROWC + l4 * 8];
#pragma unroll
    for (int kt = 0; kt < 16; ++kt) {
      bf16x8 a0 = *reinterpret_cast<const bf16x8*>(ab + kt * 32);
      bf16x8 a1 = *reinterpret_cast<const bf16x8*>(ab + 16 * ROWC + kt * 32);
#pragma unroll
      for (int n = 0; n < 4; ++n) {
        bf16x8 bb = *reinterpret_cast<const bf16x8*>(pc + ((size_t)n * 16 + kt) * 512);
        acc[0][n] = __builtin_amdgcn_mfma_f32_16x16x32_bf16(a0, bb, acc[0][n], 0, 0, 0);
        acc[1][n] = __builtin_amdgcn_mfma_f32_16x16x32_bf16(a1, bb, acc[1][n], 0, 0, 0);
      }
    }
#pragma unroll
    for (int m = 0; m < 2; ++m)
#pragma unroll
      for (int r = 0; r < 4; ++r)
#pragma unroll
        for (int n = 0; n < 4; ++n) {
          const int col = wave * 64 + n * 16 + l15;
          o3[(node0 + m * 16 + l4 * 4 + r) * 512 + col] = acc[m][n][r] + b_comb[col];
        }
  }
  {
    f32x4 acc[2][4];
#pragma unroll
    for (int m = 0; m < 2; ++m)
#pragma unroll
      for (int n = 0; n < 4; ++n) acc[m][n] = (f32x4){0.f, 0.f, 0.f, 0.f};
    const unsigned short* pa = Pa + (size_t)nt0 * 8 * 512 + lane * 8;
    const unsigned short* ab = &Aagg[(size_t)l15 * ROWA + l4 * 8];
#pragma unroll
    for (int kt = 0; kt < 8; ++kt) {
      bf16x8 a0 = *reinterpret_cast<const bf16x8*>(ab + kt * 32);
      bf16x8 a1 = *reinterpret_cast<const bf16x8*>(ab + 16 * ROWA + kt * 32);
#pragma unroll
      for (int n = 0; n < 4; ++n) {
        bf16x8 bb = *reinterpret_cast<const bf16x8*>(pa + ((size_t)n * 8 + kt) * 512);
        acc[0][n] = __builtin_amdgcn_mfma_f32_16x16x32_bf16(a0, bb, acc[0][n], 0, 0, 0);
        acc[1][n] = __builtin_amdgcn_mfma_f32_16x16x32_bf16(a1, bb, acc[1][n], 0, 0, 0);
      }
    }
#pragma unroll
    for (int m = 0; m < 2; ++m)
#pragma unroll
      for (int r = 0; r < 4; ++r)
#pragma unroll
        for (int n = 0; n < 4; ++n) {
          const int col = wave * 64 + n * 16 + l15;
          o4[(node0 + m * 16 + l4 * 4 + r) * 512 + col] = acc[m][n][r] + b_agg[col];
        }
  }
}

extern "C" void kernel_launch(void* const* d_in, const int* in_sizes, int n_in,
                              void* d_out, int out_size, void* d_ws, size_t ws_size,
                              hipStream_t stream) {
  const float* out1 = (const float*)d_in[0];
  const float* out2 = (const float*)d_in[1];
  const int* nbr = (const int*)d_in[2];  // harness pushes integers as int32
  const float* Wc = (const float*)d_in[3];
  const float* bc = (const float*)d_in[4];
  const float* Wa = (const float*)d_in[5];
  const float* ba = (const float*)d_in[6];

  const size_t yElems = (size_t)N_NODES * 512;     // bf16 Y: 204.8 MB
  const size_t packElems = 512 * 512 + 512 * 256;  // 768 KB
  const size_t need = (yElems + packElems) * 2;

  if (ws_size >= need) {
    unsigned short* Yw = (unsigned short*)d_ws;
    unsigned short* Pc = Yw + yElems;
    unsigned short* Pa = Pc + 512 * 512;
    pack_w_kernel<<<192, 256, 0, stream>>>(Wc, Wa, Pc, Pa);
    gemm_kernel<<<NTILES, 512, 0, stream>>>(out1, out2, Pc, Pa, bc, (float*)d_out, Yw);
    gather_kernel<<<GRID_B, 256, 0, stream>>>(Yw, nbr, ba,
                                              (float*)d_out + (size_t)N_NODES * 512);
  } else {
    unsigned short* Pc = (unsigned short*)d_ws;
    unsigned short* Pa = Pc + 512 * 512;
    pack_w_kernel<<<192, 256, 0, stream>>>(Wc, Wa, Pc, Pa);
    mesh_fused_fallback<<<N_NODES / 32, 512, 0, stream>>>(out1, out2, nbr, Pc, Pa, bc, ba,
                                                          (float*)d_out);
  }
}